// Round 1
// baseline (744.586 us; speedup 1.0000x reference)
//
#include <hip/hip_runtime.h>
#include <stdint.h>

// ---------------------------------------------------------------------------
// LayerNormDenseGeneral: y = LN(x)*scale+bias; z = y @ W.  Outputs (z, y).
// Shapes: x[S,B,H]=[2048,4,2048] fp32, W[H,F]=[2048,8192] fp32.
// Strategy: exact fp32 LN -> y (output 1) + bf16 copy of y in ws;
// transpose-cast W to bf16 [F][K] in ws; m97-style bf16 MFMA GEMM -> z fp32.
// bf16 rounding error absmax ~0.01 << 0.112 threshold.
// ws layout: [0, M*K*2) = A bf16 ; [M*K*2, M*K*2 + F*K*2) = Bt bf16. 64 MiB.
// ---------------------------------------------------------------------------

typedef __attribute__((ext_vector_type(8))) short short8;   // 8 x bf16 bits
typedef __attribute__((ext_vector_type(4))) float floatx4;  // MFMA acc

__device__ __forceinline__ unsigned short f2bf(float f) {
    unsigned u = __builtin_bit_cast(unsigned, f);
    u += 0x7fffu + ((u >> 16) & 1u);   // round-to-nearest-even
    return (unsigned short)(u >> 16);
}

// ---------------- LayerNorm: one block per row, H=2048 ---------------------
__global__ __launch_bounds__(256) void ln_kernel(
    const float* __restrict__ x, const float* __restrict__ scale,
    const float* __restrict__ bias, float* __restrict__ y,
    unsigned short* __restrict__ ybf, int H)
{
    const int row = blockIdx.x;
    const float* xr = x + (size_t)row * H;
    const int tid = threadIdx.x;

    // H = 2048: each thread handles float4 at [tid] and [tid+256]
    float4 v0 = ((const float4*)xr)[tid];
    float4 v1 = ((const float4*)xr)[tid + 256];

    float s  = v0.x + v0.y + v0.z + v0.w + v1.x + v1.y + v1.z + v1.w;
    float ss = v0.x*v0.x + v0.y*v0.y + v0.z*v0.z + v0.w*v0.w
             + v1.x*v1.x + v1.y*v1.y + v1.z*v1.z + v1.w*v1.w;

    // wave(64) reduce
    #pragma unroll
    for (int off = 32; off > 0; off >>= 1) {
        s  += __shfl_down(s,  off, 64);
        ss += __shfl_down(ss, off, 64);
    }
    __shared__ float rs[4], rq[4];
    if ((tid & 63) == 0) { rs[tid >> 6] = s; rq[tid >> 6] = ss; }
    __syncthreads();
    float ts = rs[0] + rs[1] + rs[2] + rs[3];
    float tq = rq[0] + rq[1] + rq[2] + rq[3];
    float mean = ts / (float)H;
    float var  = tq / (float)H - mean * mean;
    float rstd = rsqrtf(var + 1e-6f);

    float4 sc0 = ((const float4*)scale)[tid];
    float4 sc1 = ((const float4*)scale)[tid + 256];
    float4 b0  = ((const float4*)bias)[tid];
    float4 b1  = ((const float4*)bias)[tid + 256];

    float4 o0, o1;
    o0.x = (v0.x - mean) * rstd * sc0.x + b0.x;
    o0.y = (v0.y - mean) * rstd * sc0.y + b0.y;
    o0.z = (v0.z - mean) * rstd * sc0.z + b0.z;
    o0.w = (v0.w - mean) * rstd * sc0.w + b0.w;
    o1.x = (v1.x - mean) * rstd * sc1.x + b1.x;
    o1.y = (v1.y - mean) * rstd * sc1.y + b1.y;
    o1.z = (v1.z - mean) * rstd * sc1.z + b1.z;
    o1.w = (v1.w - mean) * rstd * sc1.w + b1.w;

    float* yr = y + (size_t)row * H;
    ((float4*)yr)[tid]       = o0;
    ((float4*)yr)[tid + 256] = o1;

    unsigned short* br = ybf + (size_t)row * H;
    uint2 p0, p1;
    p0.x = (unsigned)f2bf(o0.x) | ((unsigned)f2bf(o0.y) << 16);
    p0.y = (unsigned)f2bf(o0.z) | ((unsigned)f2bf(o0.w) << 16);
    p1.x = (unsigned)f2bf(o1.x) | ((unsigned)f2bf(o1.y) << 16);
    p1.y = (unsigned)f2bf(o1.z) | ((unsigned)f2bf(o1.w) << 16);
    ((uint2*)br)[tid]       = p0;
    ((uint2*)br)[tid + 256] = p1;
}

// -------- transpose-cast: W[K][F] fp32 -> Bt[F][K] bf16, 64x64 tiles -------
__global__ __launch_bounds__(256) void transpose_cast_kernel(
    const float* __restrict__ W, unsigned short* __restrict__ Bt,
    int K, int F)
{
    __shared__ float tile[64][65];
    const int kBase = blockIdx.y * 64;
    const int fBase = blockIdx.x * 64;
    const int tid = threadIdx.x;

    // read: 4 passes x (16 rows of 64 floats), coalesced float4
    #pragma unroll
    for (int p = 0; p < 4; ++p) {
        int kl = (tid >> 4) + p * 16;
        int fl = (tid & 15) * 4;
        float4 v = *(const float4*)&W[(size_t)(kBase + kl) * F + fBase + fl];
        tile[kl][fl]     = v.x;
        tile[kl][fl + 1] = v.y;
        tile[kl][fl + 2] = v.z;
        tile[kl][fl + 3] = v.w;
    }
    __syncthreads();

    // write: 2 passes x (32 f-rows), each thread packs 8 bf16 = 16B store
    #pragma unroll
    for (int p = 0; p < 2; ++p) {
        int fl = (tid >> 3) + p * 32;
        int k8 = (tid & 7) * 8;
        unsigned w[4];
        #pragma unroll
        for (int j = 0; j < 4; ++j) {
            unsigned lo = f2bf(tile[k8 + 2*j][fl]);
            unsigned hi = f2bf(tile[k8 + 2*j + 1][fl]);
            w[j] = lo | (hi << 16);
        }
        uint4 out = make_uint4(w[0], w[1], w[2], w[3]);
        *(uint4*)&Bt[(size_t)(fBase + fl) * K + kBase + k8] = out;
    }
}

// ---------------- GEMM: C[M][N] = A[M][K] * Bt[N][K]^T (bf16 -> fp32) ------
// 128x128 tile, BK=32, 256 threads = 4 waves (2x2), each wave 64x64 = 4x4
// mfma_f32_16x16x32_bf16 fragments; global_load_lds width=16 staging.
#define BM 128
#define BN 128
#define BK 32

__global__ __launch_bounds__(256) void gemm_bf16_bt(
    const unsigned short* __restrict__ A,   // [M][K] bf16
    const unsigned short* __restrict__ Bt,  // [N][K] bf16
    float* __restrict__ C,                  // [M][N] fp32
    int M, int N, int K)
{
    __shared__ unsigned short lsA[BM * BK];  // row-major [128][32]
    __shared__ unsigned short lsB[BN * BK];  // row-major [128][32]

    const int tid   = threadIdx.x;
    const int lane  = tid & 63;
    const int wave  = tid >> 6;     // 0..3
    const int waveM = wave >> 1;    // 0..1
    const int waveN = wave & 1;     // 0..1
    const int quad  = lane >> 4;    // 0..3
    const int l16   = lane & 15;

    const int bm = blockIdx.y * BM;
    const int bn = blockIdx.x * BN;

    const unsigned short* gA = A  + (size_t)bm * K;
    const unsigned short* gB = Bt + (size_t)bn * K;

    floatx4 acc[4][4] = {};

    for (int k0 = 0; k0 < K; k0 += BK) {
        __syncthreads();   // previous iteration's fragment reads complete
        // stage A tile: 128 rows x 32 bf16 (64B/row) = 8KB -> 2 issues/thread
        #pragma unroll
        for (int i = 0; i < 2; ++i) {
            int e   = i * 256 + tid;     // 16B segment index, 0..511
            int row = e >> 2;
            int cs  = e & 3;             // which 16B of the 64B row
            __builtin_amdgcn_global_load_lds(
                (const __attribute__((address_space(1))) unsigned int*)
                    (gA + (size_t)row * K + k0 + cs * 8),
                (__attribute__((address_space(3))) unsigned int*)
                    (lsA + (size_t)e * 8),
                16, 0, 0);
        }
        #pragma unroll
        for (int i = 0; i < 2; ++i) {
            int e   = i * 256 + tid;
            int row = e >> 2;
            int cs  = e & 3;
            __builtin_amdgcn_global_load_lds(
                (const __attribute__((address_space(1))) unsigned int*)
                    (gB + (size_t)row * K + k0 + cs * 8),
                (__attribute__((address_space(3))) unsigned int*)
                    (lsB + (size_t)e * 8),
                16, 0, 0);
        }
        __syncthreads();   // staging visible to all waves

        short8 a[4], b[4];
        #pragma unroll
        for (int mi = 0; mi < 4; ++mi)
            a[mi] = *(const short8*)&lsA[(waveM*64 + mi*16 + l16) * BK + quad*8];
        #pragma unroll
        for (int ni = 0; ni < 4; ++ni)
            b[ni] = *(const short8*)&lsB[(waveN*64 + ni*16 + l16) * BK + quad*8];

        #pragma unroll
        for (int mi = 0; mi < 4; ++mi)
            #pragma unroll
            for (int ni = 0; ni < 4; ++ni)
                acc[mi][ni] = __builtin_amdgcn_mfma_f32_16x16x32_bf16(
                    a[mi], b[ni], acc[mi][ni], 0, 0, 0);
    }

    // epilogue: C/D layout col = lane&15, row = quad*4 + reg
    #pragma unroll
    for (int mi = 0; mi < 4; ++mi) {
        #pragma unroll
        for (int ni = 0; ni < 4; ++ni) {
            int col = bn + waveN*64 + ni*16 + l16;
            #pragma unroll
            for (int r = 0; r < 4; ++r) {
                int row = bm + waveM*64 + mi*16 + quad*4 + r;
                C[(size_t)row * N + col] = acc[mi][ni][r];
            }
        }
    }
}

// ---------------------------------------------------------------------------
extern "C" void kernel_launch(void* const* d_in, const int* in_sizes, int n_in,
                              void* d_out, int out_size, void* d_ws, size_t ws_size,
                              hipStream_t stream) {
    const float* x      = (const float*)d_in[0];
    const float* scale  = (const float*)d_in[1];
    const float* lnbias = (const float*)d_in[2];
    const float* W      = (const float*)d_in[3];

    const int H = in_sizes[1];                 // 2048
    const int M = in_sizes[0] / H;             // S*B = 8192
    const int F = in_sizes[3] / H;             // 8192

    float* z = (float*)d_out;                  // [M][F]
    float* y = z + (size_t)M * F;              // [M][H]

    unsigned short* Abf = (unsigned short*)d_ws;            // [M][H] bf16
    unsigned short* Btb = Abf + (size_t)M * H;              // [F][H] bf16

    ln_kernel<<<M, 256, 0, stream>>>(x, scale, lnbias, y, Abf, H);
    transpose_cast_kernel<<<dim3(F / 64, H / 64), 256, 0, stream>>>(W, Btb, H, F);
    gemm_bf16_bt<<<dim3(F / BN, M / BM), 256, 0, stream>>>(Abf, Btb, z, M, F, H);
}

// Round 2
// 744.269 us; speedup vs baseline: 1.0004x; 1.0004x over previous
//
#include <hip/hip_runtime.h>
#include <stdint.h>

// ---------------------------------------------------------------------------
// LayerNormDenseGeneral: y = LN(x)*scale+bias; z = y @ W.  Outputs (z, y).
// Shapes: x[S,B,H]=[2048,4,2048] fp32, W[H,F]=[2048,8192] fp32.
// Strategy: exact fp32 LN -> y (output 1) + bf16 copy of y in ws;
// transpose-cast W to bf16 [F][K] in ws; m97-style bf16 MFMA GEMM -> z fp32.
// Round 2: XOR-swizzled LDS chunk layout in GEMM to kill the 8-way
// ds_read_b128 bank conflict (SQ_LDS_BANK_CONFLICT 3.36e7 -> ~0).
// ws layout: [0, M*K*2) = A bf16 ; [M*K*2, M*K*2 + F*K*2) = Bt bf16. 64 MiB.
// ---------------------------------------------------------------------------

typedef __attribute__((ext_vector_type(8))) short short8;   // 8 x bf16 bits
typedef __attribute__((ext_vector_type(4))) float floatx4;  // MFMA acc

__device__ __forceinline__ unsigned short f2bf(float f) {
    unsigned u = __builtin_bit_cast(unsigned, f);
    u += 0x7fffu + ((u >> 16) & 1u);   // round-to-nearest-even
    return (unsigned short)(u >> 16);
}

// ---------------- LayerNorm: one block per row, H=2048 ---------------------
__global__ __launch_bounds__(256) void ln_kernel(
    const float* __restrict__ x, const float* __restrict__ scale,
    const float* __restrict__ bias, float* __restrict__ y,
    unsigned short* __restrict__ ybf, int H)
{
    const int row = blockIdx.x;
    const float* xr = x + (size_t)row * H;
    const int tid = threadIdx.x;

    // H = 2048: each thread handles float4 at [tid] and [tid+256]
    float4 v0 = ((const float4*)xr)[tid];
    float4 v1 = ((const float4*)xr)[tid + 256];

    float s  = v0.x + v0.y + v0.z + v0.w + v1.x + v1.y + v1.z + v1.w;
    float ss = v0.x*v0.x + v0.y*v0.y + v0.z*v0.z + v0.w*v0.w
             + v1.x*v1.x + v1.y*v1.y + v1.z*v1.z + v1.w*v1.w;

    // wave(64) reduce
    #pragma unroll
    for (int off = 32; off > 0; off >>= 1) {
        s  += __shfl_down(s,  off, 64);
        ss += __shfl_down(ss, off, 64);
    }
    __shared__ float rs[4], rq[4];
    if ((tid & 63) == 0) { rs[tid >> 6] = s; rq[tid >> 6] = ss; }
    __syncthreads();
    float ts = rs[0] + rs[1] + rs[2] + rs[3];
    float tq = rq[0] + rq[1] + rq[2] + rq[3];
    float mean = ts / (float)H;
    float var  = tq / (float)H - mean * mean;
    float rstd = rsqrtf(var + 1e-6f);

    float4 sc0 = ((const float4*)scale)[tid];
    float4 sc1 = ((const float4*)scale)[tid + 256];
    float4 b0  = ((const float4*)bias)[tid];
    float4 b1  = ((const float4*)bias)[tid + 256];

    float4 o0, o1;
    o0.x = (v0.x - mean) * rstd * sc0.x + b0.x;
    o0.y = (v0.y - mean) * rstd * sc0.y + b0.y;
    o0.z = (v0.z - mean) * rstd * sc0.z + b0.z;
    o0.w = (v0.w - mean) * rstd * sc0.w + b0.w;
    o1.x = (v1.x - mean) * rstd * sc1.x + b1.x;
    o1.y = (v1.y - mean) * rstd * sc1.y + b1.y;
    o1.z = (v1.z - mean) * rstd * sc1.z + b1.z;
    o1.w = (v1.w - mean) * rstd * sc1.w + b1.w;

    float* yr = y + (size_t)row * H;
    ((float4*)yr)[tid]       = o0;
    ((float4*)yr)[tid + 256] = o1;

    unsigned short* br = ybf + (size_t)row * H;
    uint2 p0, p1;
    p0.x = (unsigned)f2bf(o0.x) | ((unsigned)f2bf(o0.y) << 16);
    p0.y = (unsigned)f2bf(o0.z) | ((unsigned)f2bf(o0.w) << 16);
    p1.x = (unsigned)f2bf(o1.x) | ((unsigned)f2bf(o1.y) << 16);
    p1.y = (unsigned)f2bf(o1.z) | ((unsigned)f2bf(o1.w) << 16);
    ((uint2*)br)[tid]       = p0;
    ((uint2*)br)[tid + 256] = p1;
}

// -------- transpose-cast: W[K][F] fp32 -> Bt[F][K] bf16, 64x64 tiles -------
__global__ __launch_bounds__(256) void transpose_cast_kernel(
    const float* __restrict__ W, unsigned short* __restrict__ Bt,
    int K, int F)
{
    __shared__ float tile[64][65];
    const int kBase = blockIdx.y * 64;
    const int fBase = blockIdx.x * 64;
    const int tid = threadIdx.x;

    // read: 4 passes x (16 rows of 64 floats), coalesced float4
    #pragma unroll
    for (int p = 0; p < 4; ++p) {
        int kl = (tid >> 4) + p * 16;
        int fl = (tid & 15) * 4;
        float4 v = *(const float4*)&W[(size_t)(kBase + kl) * F + fBase + fl];
        tile[kl][fl]     = v.x;
        tile[kl][fl + 1] = v.y;
        tile[kl][fl + 2] = v.z;
        tile[kl][fl + 3] = v.w;
    }
    __syncthreads();

    // write: 2 passes x (32 f-rows), each thread packs 8 bf16 = 16B store
    #pragma unroll
    for (int p = 0; p < 2; ++p) {
        int fl = (tid >> 3) + p * 32;
        int k8 = (tid & 7) * 8;
        unsigned w[4];
        #pragma unroll
        for (int j = 0; j < 4; ++j) {
            unsigned lo = f2bf(tile[k8 + 2*j][fl]);
            unsigned hi = f2bf(tile[k8 + 2*j + 1][fl]);
            w[j] = lo | (hi << 16);
        }
        uint4 out = make_uint4(w[0], w[1], w[2], w[3]);
        *(uint4*)&Bt[(size_t)(fBase + fl) * K + kBase + k8] = out;
    }
}

// ---------------- GEMM: C[M][N] = A[M][K] * Bt[N][K]^T (bf16 -> fp32) ------
// 128x128 tile, BK=32, 256 threads = 4 waves (2x2), each wave 64x64 = 4x4
// mfma_f32_16x16x32_bf16 fragments; global_load_lds width=16 staging.
// LDS chunk layout XOR-swizzled: slot s of row r holds global 16B-chunk
// s ^ ((r>>1)&3). Fragment ds_read_b128 then spreads 16 lanes over all 32
// banks (exactly 2-way = free, m136) instead of 8-way.
#define BM 128
#define BN 128
#define BK 32

__global__ __launch_bounds__(256) void gemm_bf16_bt(
    const unsigned short* __restrict__ A,   // [M][K] bf16
    const unsigned short* __restrict__ Bt,  // [N][K] bf16
    float* __restrict__ C,                  // [M][N] fp32
    int M, int N, int K)
{
    __shared__ unsigned short lsA[BM * BK];  // row-major [128][32], swizzled
    __shared__ unsigned short lsB[BN * BK];  // row-major [128][32], swizzled

    const int tid   = threadIdx.x;
    const int lane  = tid & 63;
    const int wave  = tid >> 6;     // 0..3
    const int waveM = wave >> 1;    // 0..1
    const int waveN = wave & 1;     // 0..1
    const int quad  = lane >> 4;    // 0..3
    const int l16   = lane & 15;
    // fragment rows are base16 + l16 with base16 % 16 == 0, so the row-xor
    // term (row>>1)&3 reduces to the lane-constant (l16>>1)&3:
    const int qswz  = (quad ^ ((l16 >> 1) & 3)) * 8;   // swizzled chunk offset (shorts)

    const int bm = blockIdx.y * BM;
    const int bn = blockIdx.x * BN;

    const unsigned short* gA = A  + (size_t)bm * K;
    const unsigned short* gB = Bt + (size_t)bn * K;

    floatx4 acc[4][4] = {};

    for (int k0 = 0; k0 < K; k0 += BK) {
        __syncthreads();   // previous iteration's fragment reads complete
        // stage A tile: 128 rows x 32 bf16 (64B/row) = 8KB -> 2 issues/thread
        // slot e&3 of row e>>2 receives global chunk (e&3)^((row>>1)&3)
        #pragma unroll
        for (int i = 0; i < 2; ++i) {
            int e   = i * 256 + tid;     // 16B slot index, 0..511
            int row = e >> 2;
            int cs  = (e & 3) ^ ((row >> 1) & 3);
            __builtin_amdgcn_global_load_lds(
                (const __attribute__((address_space(1))) unsigned int*)
                    (gA + (size_t)row * K + k0 + cs * 8),
                (__attribute__((address_space(3))) unsigned int*)
                    (lsA + (size_t)e * 8),
                16, 0, 0);
        }
        #pragma unroll
        for (int i = 0; i < 2; ++i) {
            int e   = i * 256 + tid;
            int row = e >> 2;
            int cs  = (e & 3) ^ ((row >> 1) & 3);
            __builtin_amdgcn_global_load_lds(
                (const __attribute__((address_space(1))) unsigned int*)
                    (gB + (size_t)row * K + k0 + cs * 8),
                (__attribute__((address_space(3))) unsigned int*)
                    (lsB + (size_t)e * 8),
                16, 0, 0);
        }
        __syncthreads();   // staging visible to all waves

        short8 a[4], b[4];
        #pragma unroll
        for (int mi = 0; mi < 4; ++mi)
            a[mi] = *(const short8*)&lsA[(waveM*64 + mi*16 + l16) * BK + qswz];
        #pragma unroll
        for (int ni = 0; ni < 4; ++ni)
            b[ni] = *(const short8*)&lsB[(waveN*64 + ni*16 + l16) * BK + qswz];

        #pragma unroll
        for (int mi = 0; mi < 4; ++mi)
            #pragma unroll
            for (int ni = 0; ni < 4; ++ni)
                acc[mi][ni] = __builtin_amdgcn_mfma_f32_16x16x32_bf16(
                    a[mi], b[ni], acc[mi][ni], 0, 0, 0);
    }

    // epilogue: C/D layout col = lane&15, row = quad*4 + reg
    #pragma unroll
    for (int mi = 0; mi < 4; ++mi) {
        #pragma unroll
        for (int ni = 0; ni < 4; ++ni) {
            int col = bn + waveN*64 + ni*16 + l16;
            #pragma unroll
            for (int r = 0; r < 4; ++r) {
                int row = bm + waveM*64 + mi*16 + quad*4 + r;
                C[(size_t)row * N + col] = acc[mi][ni][r];
            }
        }
    }
}

// ---------------------------------------------------------------------------
extern "C" void kernel_launch(void* const* d_in, const int* in_sizes, int n_in,
                              void* d_out, int out_size, void* d_ws, size_t ws_size,
                              hipStream_t stream) {
    const float* x      = (const float*)d_in[0];
    const float* scale  = (const float*)d_in[1];
    const float* lnbias = (const float*)d_in[2];
    const float* W      = (const float*)d_in[3];

    const int H = in_sizes[1];                 // 2048
    const int M = in_sizes[0] / H;             // S*B = 8192
    const int F = in_sizes[3] / H;             // 8192

    float* z = (float*)d_out;                  // [M][F]
    float* y = z + (size_t)M * F;              // [M][H]

    unsigned short* Abf = (unsigned short*)d_ws;            // [M][H] bf16
    unsigned short* Btb = Abf + (size_t)M * H;              // [F][H] bf16

    ln_kernel<<<M, 256, 0, stream>>>(x, scale, lnbias, y, Abf, H);
    transpose_cast_kernel<<<dim3(F / 64, H / 64), 256, 0, stream>>>(W, Btb, H, F);
    gemm_bf16_bt<<<dim3(F / BN, M / BM), 256, 0, stream>>>(Abf, Btb, z, M, F, H);
}